// Round 3
// baseline (68531.250 us; speedup 1.0000x reference)
//
#include <hip/hip_runtime.h>
#include <hip/hip_bf16.h>

#define T_ 256
#define B_ 128
#define H_ 512
#define G3 1536

typedef __attribute__((ext_vector_type(8))) short short8;
typedef __attribute__((ext_vector_type(4))) short short4v;
typedef __attribute__((ext_vector_type(4))) float f32x4;

static __device__ __forceinline__ float b2f(short s){
    unsigned u = ((unsigned)(unsigned short)s) << 16;
    return __builtin_bit_cast(float, u);
}
static __device__ __forceinline__ short f2b(float f){
    __hip_bfloat16 h = __float2bfloat16(f);   // RNE
    return __builtin_bit_cast(short, h);
}
static __device__ __forceinline__ void gload16(const void* g, void* l){
    __builtin_amdgcn_global_load_lds(
        (__attribute__((address_space(1))) void*)(void*)g,
        (__attribute__((address_space(3))) void*)l, 16, 0, 0);
}

// ---------------- fp32 -> bf16 conversion ----------------
__global__ void cvt_f32_to_bf16(const float* __restrict__ src, short* __restrict__ dst, int n){
    int i = (blockIdx.x * blockDim.x + threadIdx.x) * 4;
    int stride = gridDim.x * blockDim.x * 4;
    for (; i + 3 < n; i += stride){
        float4 v = *(const float4*)(src + i);
        short4v o;
        o[0] = f2b(v.x); o[1] = f2b(v.y); o[2] = f2b(v.z); o[3] = f2b(v.w);
        *(short4v*)(dst + i) = o;
    }
}

// ---------------- gx chunk GEMM ----------------
// gxc[dir][sch*128][1536] (fp32) = IN[t0[dir]*128 ...][K] x W[dir][1536][K]^T + b_ih
// grid (sch, 12, 2), block 256 (4 waves, each 64x64 of the 128x128 tile)
__global__ __launch_bounds__(256) void gx_gemm(
    const short* __restrict__ A,     // [T*B][K] bf16 (t-major layer input)
    const short* __restrict__ W,     // [2*1536][K] bf16
    const float* __restrict__ bias,  // [2*1536] fp32
    float* __restrict__ gxc,         // [2][sch*128][1536] fp32
    int K, int t0f, int t0b_lo, int sch)
{
    __shared__ __align__(16) short sA[4096];   // [128][32]
    __shared__ __align__(16) short sB[4096];
    const int dir = blockIdx.z;
    const int t0 = dir ? t0b_lo : t0f;
    const int m0 = blockIdx.x * 128;           // local chunk row
    const int n0 = blockIdx.y * 128;
    const short* Ae = A + (size_t)(t0 * B_) * K;
    const short* We = W + (size_t)dir * G3 * K;
    float* out = gxc + (size_t)dir * ((size_t)sch * B_ * G3);

    const int tid = threadIdx.x, wv = tid >> 6, lane = tid & 63;
    const int moff = (wv & 1) * 64, noff = (wv >> 1) * 64;
    const int e0 = wv * 1024 + lane * 8, e1 = e0 + 512;
    const short* a0 = Ae + (size_t)(m0 + (e0 >> 5)) * K + (e0 & 31);
    const short* a1 = Ae + (size_t)(m0 + (e1 >> 5)) * K + (e1 & 31);
    const short* b0 = We + (size_t)(n0 + (e0 >> 5)) * K + (e0 & 31);
    const short* b1 = We + (size_t)(n0 + (e1 >> 5)) * K + (e1 & 31);
    short* sa0 = &sA[wv * 1024];  short* sa1 = &sA[wv * 1024 + 512];
    short* sb0 = &sB[wv * 1024];  short* sb1 = &sB[wv * 1024 + 512];

    f32x4 acc[4][4] = {};
    const int lr = lane & 15, lk = (lane >> 4) * 8;

    for (int kk = 0; kk < K; kk += 32){
        gload16(a0 + kk, sa0); gload16(a1 + kk, sa1);
        gload16(b0 + kk, sb0); gload16(b1 + kk, sb1);
        __syncthreads();                      // drains vmcnt: tiles ready
        short8 ar[4], br[4];
        #pragma unroll
        for (int i = 0; i < 4; ++i) ar[i] = *(const short8*)&sA[(moff + i*16 + lr) * 32 + lk];
        #pragma unroll
        for (int i = 0; i < 4; ++i) br[i] = *(const short8*)&sB[(noff + i*16 + lr) * 32 + lk];
        #pragma unroll
        for (int ai = 0; ai < 4; ++ai)
            #pragma unroll
            for (int bi = 0; bi < 4; ++bi)
                acc[ai][bi] = __builtin_amdgcn_mfma_f32_16x16x32_bf16(ar[ai], br[bi], acc[ai][bi], 0, 0, 0);
        __syncthreads();
    }

    #pragma unroll
    for (int ai = 0; ai < 4; ++ai){
        #pragma unroll
        for (int bi = 0; bi < 4; ++bi){
            int col = n0 + noff + bi*16 + lr;
            float bv = bias[dir * G3 + col];
            #pragma unroll
            for (int r = 0; r < 4; ++r){
                int row = m0 + moff + ai*16 + ((lane >> 4) << 2) + r;
                out[(size_t)row * G3 + col] = acc[ai][bi][r] + bv;
            }
        }
    }
}

// ---------------- per-phase recurrence ----------------
// grid (8 bg, 2 dir), block 512 (8 waves). Wave wv: units [wv*64, wv*64+64) x 3 gates.
// Whh streamed from L2 each step; h bf16 double-buffered in LDS; fp32 h in regs,
// persisted to hf between phase launches. One barrier per step.
__global__ __launch_bounds__(512) void rec_kernel(
    const float* __restrict__ gxc,   // [2][sch*128][1536] fp32 (b_ih folded)
    const short* __restrict__ Whh,   // [2*1536][512] bf16
    const float* __restrict__ bhh,   // [2*1536]
    short* __restrict__ xout,        // [T][B][1024] bf16
    float* __restrict__ hf,          // [2][128][512] fp32
    int sch, int t0f, int t0b_hi, int first)
{
    __shared__ __align__(16) short hlds[2][16][520];
    const int tid = threadIdx.x, wv = tid >> 6, lane = tid & 63;
    const int bg = blockIdx.x, dir = blockIdx.y;
    const int row0 = bg * 16;
    const int u0 = wv * 64;
    const int lr = lane & 15, lk = (lane >> 4) * 8;
    const int crow = (lane >> 4) * 4;

    const short* Wd = Whh + (size_t)dir * G3 * H_;
    const float* gxd = gxc + (size_t)dir * ((size_t)sch * B_ * G3);

    float bh[3][4];
    #pragma unroll
    for (int g = 0; g < 3; ++g)
        #pragma unroll
        for (int ut = 0; ut < 4; ++ut)
            bh[g][ut] = bhh[dir*G3 + g*H_ + u0 + ut*16 + lr];

    float hreg[4][4];
    #pragma unroll
    for (int ut = 0; ut < 4; ++ut)
        #pragma unroll
        for (int r = 0; r < 4; ++r){
            float hv = first ? 0.f
                : hf[((size_t)dir*B_ + row0 + crow + r)*H_ + u0 + ut*16 + lr];
            hreg[ut][r] = hv;
            hlds[0][crow + r][u0 + ut*16 + lr] = f2b(hv);
        }
    __syncthreads();

    int cur = 0;
    for (int sl = 0; sl < sch; ++sl){
        const int t  = dir ? (t0b_hi - sl) : (t0f + sl);
        const int tl = dir ? (sch - 1 - sl) : sl;    // chunk-local index

        // gx loads (fp32, coalesced 16x4B per (g,ut,r)) — issued early
        const float* gbase = gxd + ((size_t)tl * B_ + row0 + crow) * G3 + u0 + lr;
        float gv[3][4][4];
        #pragma unroll
        for (int g = 0; g < 3; ++g)
            #pragma unroll
            for (int ut = 0; ut < 4; ++ut)
                #pragma unroll
                for (int r = 0; r < 4; ++r)
                    gv[g][ut][r] = gbase[(size_t)r * G3 + g*H_ + ut*16];

        f32x4 acc[3][4] = {};
        #pragma unroll
        for (int kk = 0; kk < 16; ++kk){
            short8 a = *(const short8*)&hlds[cur][lr][kk*32 + lk];
            #pragma unroll
            for (int g = 0; g < 3; ++g)
                #pragma unroll
                for (int ut = 0; ut < 4; ++ut){
                    short8 b = *(const short8*)&Wd[((size_t)(g*H_ + u0 + ut*16 + lr)) * H_ + kk*32 + lk];
                    acc[g][ut] = __builtin_amdgcn_mfma_f32_16x16x32_bf16(a, b, acc[g][ut], 0, 0, 0);
                }
        }

        #pragma unroll
        for (int ut = 0; ut < 4; ++ut){
            #pragma unroll
            for (int r = 0; r < 4; ++r){
                float gr = acc[0][ut][r] + bh[0][ut] + gv[0][ut][r];
                float gz = acc[1][ut][r] + bh[1][ut] + gv[1][ut][r];
                float gn = acc[2][ut][r] + bh[2][ut];
                float xn = gv[2][ut][r];
                float rg = 1.f / (1.f + __expf(-gr));
                float zg = 1.f / (1.f + __expf(-gz));
                float e2 = __expf(2.f * (xn + rg * gn));
                float ng = 1.f - 2.f / (e2 + 1.f);            // tanh, inf-safe
                float hn = (1.f - zg) * ng + zg * hreg[ut][r];
                hreg[ut][r] = hn;
                short h16 = f2b(hn);
                hlds[cur ^ 1][crow + r][u0 + ut*16 + lr] = h16;
                xout[((size_t)t * B_ + row0 + crow + r) * 1024 + dir*H_ + u0 + ut*16 + lr] = h16;
            }
        }
        __syncthreads();
        cur ^= 1;
    }

    #pragma unroll
    for (int ut = 0; ut < 4; ++ut)
        #pragma unroll
        for (int r = 0; r < 4; ++r)
            hf[((size_t)dir*B_ + row0 + crow + r)*H_ + u0 + ut*16 + lr] = hreg[ut][r];
}

// ---------------- final FC + sigmoid ----------------
__global__ void fc_kernel(const short* __restrict__ h, const float* __restrict__ w,
                          const float* __restrict__ b, float* __restrict__ out){
    int wid = threadIdx.x >> 6, lane = threadIdx.x & 63;
    int tb = blockIdx.x * 4 + wid;
    const short* hp = h + (size_t)tb * 1024 + lane * 16;
    float s = 0.f;
    #pragma unroll
    for (int c = 0; c < 2; ++c){
        short8 v = *(const short8*)(hp + c * 8);
        #pragma unroll
        for (int e = 0; e < 8; ++e) s += b2f(v[e]) * w[lane * 16 + c * 8 + e];
    }
    #pragma unroll
    for (int o = 32; o; o >>= 1) s += __shfl_down(s, o);
    if (lane == 0) out[tb] = 1.f / (1.f + __expf(-(s + b[0])));
}

extern "C" void kernel_launch(void* const* d_in, const int* in_sizes, int n_in,
                              void* d_out, int out_size, void* d_ws, size_t ws_size,
                              hipStream_t stream){
    const float* input_seq = (const float*)d_in[0];
    const float* W_ih0 = (const float*)d_in[1];
    const float* W_hh0 = (const float*)d_in[2];
    const float* b_ih0 = (const float*)d_in[3];
    const float* b_hh0 = (const float*)d_in[4];
    const float* W_ih  = (const float*)d_in[5];
    const float* W_hh  = (const float*)d_in[6];
    const float* b_ih  = (const float*)d_in[7];
    const float* b_hh  = (const float*)d_in[8];
    const float* fc_w  = (const float*)d_in[9];
    const float* fc_b  = (const float*)d_in[10];
    (void)in_sizes; (void)n_in; (void)out_size;

    // Adaptive chunking: NCH=8 needs ~194.5 MB of ws; NCH=16 needs ~169.4 MB
    // (round 1 proved ws >= 176.7 MB works).
    const int NCH = (ws_size >= (size_t)205*1024*1024) ? 8 : 16;
    const int SCH = T_ / NCH;

    char* ws = (char*)d_ws;
    size_t off = 0;
    auto alloc = [&](size_t bytes) -> char* {
        char* p = ws + off; off += (bytes + 255) & ~(size_t)255; return p;
    };
    short* actA = (short*)alloc((size_t)T_*B_*1024 * 2);              // 67.1 MB
    short* actB = (short*)alloc((size_t)T_*B_*1024 * 2);              // 67.1 MB
    float* gxc  = (float*)alloc((size_t)2*SCH*B_*G3 * 4);             // 25.2/50.3 MB
    short* wihl = (short*)alloc((size_t)2*G3*1024 * 2);               // 6.3 MB (per-layer)
    short* whhl = (short*)alloc((size_t)2*G3*H_ * 2);                 // 3.1 MB (per-layer)
    float* hf   = (float*)alloc((size_t)2*B_*H_ * 4);                 // 0.5 MB

    auto cvt = [&](const float* s, short* d, size_t n){
        int blocks = (int)((n/4 + 255) / 256); if (blocks > 4096) blocks = 4096;
        hipLaunchKernelGGL(cvt_f32_to_bf16, dim3(blocks), dim3(256), 0, stream, s, d, (int)n);
    };

    // layer-0 input, converted into actB's head as [T*B][128] bf16
    cvt(input_seq, actB, (size_t)T_*B_*128);

    for (int l = 0; l < 5; ++l){
        const int K = l ? 1024 : 128;
        cvt(l ? W_ih + (size_t)(l-1)*2*G3*1024 : W_ih0, wihl, (size_t)2*G3*K);
        cvt(l ? W_hh + (size_t)(l-1)*2*G3*H_   : W_hh0, whhl, (size_t)2*G3*H_);
        const short* IN  = (l & 1) ? actA : actB;
        short*       OUT = (l & 1) ? actB : actA;
        const float* bi = l ? b_ih + (size_t)(l-1)*2*G3 : b_ih0;
        const float* bh = l ? b_hh + (size_t)(l-1)*2*G3 : b_hh0;

        for (int p = 0; p < NCH; ++p){
            const int t0f    = SCH * p;
            const int t0b_hi = T_ - 1 - SCH * p;
            const int t0b_lo = t0b_hi - SCH + 1;
            hipLaunchKernelGGL(gx_gemm, dim3(SCH, 12, 2), dim3(256), 0, stream,
                               IN, wihl, bi, gxc, K, t0f, t0b_lo, SCH);
            hipLaunchKernelGGL(rec_kernel, dim3(8, 2), dim3(512), 0, stream,
                               gxc, whhl, bh, OUT, hf, SCH, t0f, t0b_hi, p == 0);
        }
    }
    // layer 4 wrote actA
    hipLaunchKernelGGL(fc_kernel, dim3((T_*B_)/4), dim3(256), 0, stream,
                       actA, fc_w, fc_b, (float*)d_out);
}

// Round 4
// 38189.270 us; speedup vs baseline: 1.7945x; 1.7945x over previous
//
#include <hip/hip_runtime.h>
#include <hip/hip_bf16.h>

#define T_ 256
#define B_ 128
#define H_ 512
#define G3 1536
#define SCH 32      // timesteps per chunk
#define NCH 8       // chunks per layer
#define RWG 32      // rec WGs per direction

typedef __attribute__((ext_vector_type(8))) short short8;
typedef __attribute__((ext_vector_type(4))) short short4v;
typedef __attribute__((ext_vector_type(4))) float f32x4;

static __device__ __forceinline__ float b2f(short s){
    unsigned u = ((unsigned)(unsigned short)s) << 16;
    return __builtin_bit_cast(float, u);
}
static __device__ __forceinline__ short f2b(float f){
    __hip_bfloat16 h = __float2bfloat16(f);   // RNE
    return __builtin_bit_cast(short, h);
}
static __device__ __forceinline__ void gload16(const void* g, void* l){
    __builtin_amdgcn_global_load_lds(
        (__attribute__((address_space(1))) void*)(void*)g,
        (__attribute__((address_space(3))) void*)l, 16, 0, 0);
}

// ---------------- fp32 -> bf16 conversion ----------------
__global__ void cvt_f32_to_bf16(const float* __restrict__ src, short* __restrict__ dst, int n){
    int i = (blockIdx.x * blockDim.x + threadIdx.x) * 4;
    int stride = gridDim.x * blockDim.x * 4;
    for (; i + 3 < n; i += stride){
        float4 v = *(const float4*)(src + i);
        short4v o;
        o[0] = f2b(v.x); o[1] = f2b(v.y); o[2] = f2b(v.z); o[3] = f2b(v.w);
        *(short4v*)(dst + i) = o;
    }
}

// ---------------- gx chunk GEMM (m97-style 128x128 tile, bf16 out) ----------------
// gxc[dir][SCH*128][1536] = IN[t0[dir]*128 ...][K] x W[dir][1536][K]^T + b_ih
__global__ __launch_bounds__(256) void gx_gemm(
    const short* __restrict__ A,     // [T*B][K] bf16
    const short* __restrict__ W,     // [2*1536][K] bf16
    const float* __restrict__ bias,  // [2*1536] fp32
    short* __restrict__ gxc,         // [2][SCH*128][1536] bf16
    int K, int t0f, int t0b_lo)
{
    __shared__ __align__(16) short sA[4096];   // [128][32]
    __shared__ __align__(16) short sB[4096];
    const int dir = blockIdx.z;
    const int t0 = dir ? t0b_lo : t0f;
    const int m0 = blockIdx.x * 128;
    const int n0 = blockIdx.y * 128;
    const short* Ae = A + (size_t)(t0 * B_) * K;
    const short* We = W + (size_t)dir * G3 * K;
    short* out = gxc + (size_t)dir * ((size_t)SCH * B_ * G3);

    const int tid = threadIdx.x, wv = tid >> 6, lane = tid & 63;
    const int moff = (wv & 1) * 64, noff = (wv >> 1) * 64;
    const int e0 = wv * 1024 + lane * 8, e1 = e0 + 512;
    const short* a0 = Ae + (size_t)(m0 + (e0 >> 5)) * K + (e0 & 31);
    const short* a1 = Ae + (size_t)(m0 + (e1 >> 5)) * K + (e1 & 31);
    const short* b0 = We + (size_t)(n0 + (e0 >> 5)) * K + (e0 & 31);
    const short* b1 = We + (size_t)(n0 + (e1 >> 5)) * K + (e1 & 31);
    short* sa0 = &sA[wv * 1024];  short* sa1 = &sA[wv * 1024 + 512];
    short* sb0 = &sB[wv * 1024];  short* sb1 = &sB[wv * 1024 + 512];

    f32x4 acc[4][4] = {};
    const int lr = lane & 15, lk = (lane >> 4) * 8;

    for (int kk = 0; kk < K; kk += 32){
        gload16(a0 + kk, sa0); gload16(a1 + kk, sa1);
        gload16(b0 + kk, sb0); gload16(b1 + kk, sb1);
        __syncthreads();
        short8 ar[4], br[4];
        #pragma unroll
        for (int i = 0; i < 4; ++i) ar[i] = *(const short8*)&sA[(moff + i*16 + lr) * 32 + lk];
        #pragma unroll
        for (int i = 0; i < 4; ++i) br[i] = *(const short8*)&sB[(noff + i*16 + lr) * 32 + lk];
        #pragma unroll
        for (int ai = 0; ai < 4; ++ai)
            #pragma unroll
            for (int bi = 0; bi < 4; ++bi)
                acc[ai][bi] = __builtin_amdgcn_mfma_f32_16x16x32_bf16(ar[ai], br[bi], acc[ai][bi], 0, 0, 0);
        __syncthreads();
    }

    #pragma unroll
    for (int ai = 0; ai < 4; ++ai){
        #pragma unroll
        for (int bi = 0; bi < 4; ++bi){
            int col = n0 + noff + bi*16 + lr;
            float bv = bias[dir * G3 + col];
            #pragma unroll
            for (int r = 0; r < 4; ++r){
                int row = m0 + moff + ai*16 + ((lane >> 4) << 2) + r;
                out[(size_t)row * G3 + col] = f2b(acc[ai][bi][r] + bv);
            }
        }
    }
}

// ---------------- persistent chunk recurrence, unit-split, weights in VGPRs ----------
// grid (RWG=32 unit-groups, 2 dirs), block 512 (8 waves = 8 M-tiles of 16 batch rows).
// Wave: units [u0,u0+16) x 3 gates, B-frags resident (192 VGPRs). h exchanged via
// global double-buffered bf16 hbb + per-dir spin barrier each step.
__global__ __launch_bounds__(512, 2) void rec_kernel(
    const short* __restrict__ gxc,   // [2][SCH*128][1536] bf16 (b_ih folded)
    const short* __restrict__ Whh,   // [2*1536][512] bf16
    const float* __restrict__ bhh,   // [2*1536] fp32
    short* __restrict__ xout,        // [T][B][1024] bf16
    float* __restrict__ hfm,         // [2][128][512] fp32 master (cross-launch)
    short* __restrict__ hbb,         // [2 parity][2 dir][128][512] bf16
    int* __restrict__ bar,           // per-dir {cnt, gen}, stride 16 ints
    int t0f, int t0b_hi, int first)
{
    const int tid = threadIdx.x, wv = tid >> 6, lane = tid & 63;
    const int ug = blockIdx.x, dir = blockIdx.y;
    const int u0 = ug * 16;
    const int m0 = wv * 16;
    const int lr = lane & 15, lk = (lane >> 4) * 8;
    const int crow = (lane >> 4) * 4;

    // ---- resident weight fragments: 3 gates x 16 k-steps (192 VGPRs)
    const short* Wd = Whh + (size_t)dir * G3 * H_;
    short8 wreg[3][16];
    #pragma unroll
    for (int g = 0; g < 3; ++g)
        #pragma unroll
        for (int kk = 0; kk < 16; ++kk)
            wreg[g][kk] = *(const short8*)&Wd[(size_t)(g*H_ + u0 + lr) * H_ + kk*32 + lk];

    float bh[3];
    #pragma unroll
    for (int g = 0; g < 3; ++g) bh[g] = bhh[dir*G3 + g*H_ + u0 + lr];

    float hreg[4];
    #pragma unroll
    for (int r = 0; r < 4; ++r)
        hreg[r] = first ? 0.f : hfm[((size_t)dir*B_ + m0 + crow + r)*H_ + u0 + lr];

    int* cnt = bar + dir * 16;
    int* gen = bar + dir * 16 + 8;
    const short* gxd = gxc + (size_t)dir * ((size_t)SCH * B_ * G3);

    for (int sl = 0; sl < SCH; ++sl){
        const int t  = dir ? (t0b_hi - sl) : (t0f + sl);
        const int tl = dir ? (SCH - 1 - sl) : sl;
        const int rp = sl & 1;

        // gate-input loads (independent of h)
        const short* gb = gxd + ((size_t)(tl * B_) + m0 + crow) * G3 + u0 + lr;
        float gv[3][4];
        #pragma unroll
        for (int g = 0; g < 3; ++g)
            #pragma unroll
            for (int r = 0; r < 4; ++r)
                gv[g][r] = b2f(gb[(size_t)r * G3 + g * H_]);

        // recurrent GEMM: A-frags from hbb[rp][dir], B resident
        const short* hread = hbb + ((size_t)(rp*2 + dir) * B_) * H_;
        f32x4 acc[3] = {};
        #pragma unroll
        for (int kk = 0; kk < 16; ++kk){
            short8 a = *(const short8*)&hread[(size_t)(m0 + lr) * H_ + kk*32 + lk];
            #pragma unroll
            for (int g = 0; g < 3; ++g)
                acc[g] = __builtin_amdgcn_mfma_f32_16x16x32_bf16(a, wreg[g][kk], acc[g], 0, 0, 0);
        }

        // gates + h update (lane: unit = u0+lr fixed, 4 batch rows)
        short* hwr = hbb + ((size_t)((rp^1)*2 + dir) * B_) * H_;
        #pragma unroll
        for (int r = 0; r < 4; ++r){
            float gr = acc[0][r] + bh[0] + gv[0][r];
            float gz = acc[1][r] + bh[1] + gv[1][r];
            float gn = acc[2][r] + bh[2];
            float xn = gv[2][r];
            float rg = 1.f / (1.f + __expf(-gr));
            float zg = 1.f / (1.f + __expf(-gz));
            float e2 = __expf(2.f * (xn + rg * gn));
            float ng = 1.f - 2.f / (e2 + 1.f);            // tanh, inf-safe
            float hn = (1.f - zg) * ng + zg * hreg[r];
            hreg[r] = hn;
            short h16 = f2b(hn);
            hwr[(size_t)(m0 + crow + r) * H_ + u0 + lr] = h16;
            xout[((size_t)t * B_ + m0 + crow + r) * 1024 + dir*H_ + u0 + lr] = h16;
        }

        // per-dir barrier: h writes visible to all 32 WGs of this dir
        __threadfence();
        __syncthreads();
        if (tid == 0){
            int g0 = __hip_atomic_load(gen, __ATOMIC_RELAXED, __HIP_MEMORY_SCOPE_AGENT);
            int a  = __hip_atomic_fetch_add(cnt, 1, __ATOMIC_ACQ_REL, __HIP_MEMORY_SCOPE_AGENT);
            if (a == RWG - 1){
                __hip_atomic_store(cnt, 0, __ATOMIC_RELAXED, __HIP_MEMORY_SCOPE_AGENT);
                __hip_atomic_store(gen, g0 + 1, __ATOMIC_RELEASE, __HIP_MEMORY_SCOPE_AGENT);
            } else {
                while (__hip_atomic_load(gen, __ATOMIC_ACQUIRE, __HIP_MEMORY_SCOPE_AGENT) == g0)
                    __builtin_amdgcn_s_sleep(1);
            }
        }
        __syncthreads();
    }

    // persist fp32 master across chunk launches
    #pragma unroll
    for (int r = 0; r < 4; ++r)
        hfm[((size_t)dir*B_ + m0 + crow + r)*H_ + u0 + lr] = hreg[r];
}

// ---------------- final FC + sigmoid ----------------
__global__ void fc_kernel(const short* __restrict__ h, const float* __restrict__ w,
                          const float* __restrict__ b, float* __restrict__ out){
    int wid = threadIdx.x >> 6, lane = threadIdx.x & 63;
    int tb = blockIdx.x * 4 + wid;
    const short* hp = h + (size_t)tb * 1024 + lane * 16;
    float s = 0.f;
    #pragma unroll
    for (int c = 0; c < 2; ++c){
        short8 v = *(const short8*)(hp + c * 8);
        #pragma unroll
        for (int e = 0; e < 8; ++e) s += b2f(v[e]) * w[lane * 16 + c * 8 + e];
    }
    #pragma unroll
    for (int o = 32; o; o >>= 1) s += __shfl_down(s, o);
    if (lane == 0) out[tb] = 1.f / (1.f + __expf(-(s + b[0])));
}

extern "C" void kernel_launch(void* const* d_in, const int* in_sizes, int n_in,
                              void* d_out, int out_size, void* d_ws, size_t ws_size,
                              hipStream_t stream){
    const float* input_seq = (const float*)d_in[0];
    const float* W_ih0 = (const float*)d_in[1];
    const float* W_hh0 = (const float*)d_in[2];
    const float* b_ih0 = (const float*)d_in[3];
    const float* b_hh0 = (const float*)d_in[4];
    const float* W_ih  = (const float*)d_in[5];
    const float* W_hh  = (const float*)d_in[6];
    const float* b_ih  = (const float*)d_in[7];
    const float* b_hh  = (const float*)d_in[8];
    const float* fc_w  = (const float*)d_in[9];
    const float* fc_b  = (const float*)d_in[10];
    (void)in_sizes; (void)n_in; (void)out_size; (void)ws_size;

    char* ws = (char*)d_ws;
    size_t off = 0;
    auto alloc = [&](size_t bytes) -> char* {
        char* p = ws + off; off += (bytes + 255) & ~(size_t)255; return p;
    };
    short* actA = (short*)alloc((size_t)T_*B_*1024 * 2);          // 67.1 MB
    short* actB = (short*)alloc((size_t)T_*B_*1024 * 2);          // 67.1 MB
    short* gxc  = (short*)alloc((size_t)2*SCH*B_*G3 * 2);         // 25.2 MB
    short* wihl = (short*)alloc((size_t)2*G3*1024 * 2);           // 6.3 MB
    short* whhl = (short*)alloc((size_t)2*G3*H_ * 2);             // 3.1 MB
    float* hfm  = (float*)alloc((size_t)2*B_*H_ * 4);             // 0.5 MB
    short* hbb  = (short*)alloc((size_t)2*2*B_*H_ * 2);           // 0.5 MB
    int*   bar  = (int*)alloc(256);

    hipMemsetAsync(bar, 0, 256, stream);

    auto cvt = [&](const float* s, short* d, size_t n){
        int blocks = (int)((n/4 + 255) / 256); if (blocks > 4096) blocks = 4096;
        hipLaunchKernelGGL(cvt_f32_to_bf16, dim3(blocks), dim3(256), 0, stream, s, d, (int)n);
    };

    // layer-0 input as [T*B][128] bf16 in actB's head
    cvt(input_seq, actB, (size_t)T_*B_*128);

    for (int l = 0; l < 5; ++l){
        const int K = l ? 1024 : 128;
        cvt(l ? W_ih + (size_t)(l-1)*2*G3*1024 : W_ih0, wihl, (size_t)2*G3*K);
        cvt(l ? W_hh + (size_t)(l-1)*2*G3*H_   : W_hh0, whhl, (size_t)2*G3*H_);
        const short* IN  = (l & 1) ? actA : actB;
        short*       OUT = (l & 1) ? actB : actA;
        const float* bi = l ? b_ih + (size_t)(l-1)*2*G3 : b_ih0;
        const float* bh = l ? b_hh + (size_t)(l-1)*2*G3 : b_hh0;

        hipMemsetAsync(hbb, 0, (size_t)2*2*B_*H_*2, stream);   // h(t=0) = 0, both parities

        for (int q = 0; q < NCH; ++q){
            const int t0f    = SCH * q;
            const int t0b_hi = T_ - 1 - SCH * q;
            const int t0b_lo = t0b_hi - SCH + 1;
            hipLaunchKernelGGL(gx_gemm, dim3(SCH*B_/128, G3/128, 2), dim3(256), 0, stream,
                               IN, wihl, bi, gxc, K, t0f, t0b_lo);
            hipLaunchKernelGGL(rec_kernel, dim3(RWG, 2), dim3(512), 0, stream,
                               gxc, whhl, bh, OUT, hfm, hbb, bar, t0f, t0b_hi, q == 0);
        }
    }
    // layer 4 wrote actA
    hipLaunchKernelGGL(fc_kernel, dim3((T_*B_)/4), dim3(256), 0, stream,
                       actA, fc_w, fc_b, (float*)d_out);
}

// Round 5
// 27311.130 us; speedup vs baseline: 2.5093x; 1.3983x over previous
//
#include <hip/hip_runtime.h>
#include <hip/hip_bf16.h>

#define T_ 256
#define B_ 128
#define H_ 512
#define G3 1536
#define SCH 32      // timesteps per chunk
#define NCH 8       // chunks per layer
#define RWG 32      // rec WGs per direction (8 unit-groups x 4 batch-groups)
#define BGRP 8      // WGs per barrier group (one bg, all ug)

typedef __attribute__((ext_vector_type(8))) short short8;
typedef __attribute__((ext_vector_type(4))) short short4v;
typedef __attribute__((ext_vector_type(4))) float f32x4;

static __device__ __forceinline__ float b2f(short s){
    unsigned u = ((unsigned)(unsigned short)s) << 16;
    return __builtin_bit_cast(float, u);
}
static __device__ __forceinline__ short f2b(float f){
    __hip_bfloat16 h = __float2bfloat16(f);   // RNE
    return __builtin_bit_cast(short, h);
}
static __device__ __forceinline__ void gload16(const void* g, void* l){
    __builtin_amdgcn_global_load_lds(
        (__attribute__((address_space(1))) void*)(void*)g,
        (__attribute__((address_space(3))) void*)l, 16, 0, 0);
}

// ---------------- fp32 -> bf16 conversion ----------------
__global__ void cvt_f32_to_bf16(const float* __restrict__ src, short* __restrict__ dst, int n){
    int i = (blockIdx.x * blockDim.x + threadIdx.x) * 4;
    int stride = gridDim.x * blockDim.x * 4;
    for (; i + 3 < n; i += stride){
        float4 v = *(const float4*)(src + i);
        short4v o;
        o[0] = f2b(v.x); o[1] = f2b(v.y); o[2] = f2b(v.z); o[3] = f2b(v.w);
        *(short4v*)(dst + i) = o;
    }
}

// ---------------- gx chunk GEMM (m97-style 128x128 tile, bf16 out) ----------------
__global__ __launch_bounds__(256) void gx_gemm(
    const short* __restrict__ A,     // [T*B][K] bf16
    const short* __restrict__ W,     // [2*1536][K] bf16
    const float* __restrict__ bias,  // [2*1536] fp32
    short* __restrict__ gxc,         // [2][SCH*128][1536] bf16
    int K, int t0f, int t0b_lo)
{
    __shared__ __align__(16) short sA[4096];   // [128][32]
    __shared__ __align__(16) short sB[4096];
    const int dir = blockIdx.z;
    const int t0 = dir ? t0b_lo : t0f;
    const int m0 = blockIdx.x * 128;
    const int n0 = blockIdx.y * 128;
    const short* Ae = A + (size_t)(t0 * B_) * K;
    const short* We = W + (size_t)dir * G3 * K;
    short* out = gxc + (size_t)dir * ((size_t)SCH * B_ * G3);

    const int tid = threadIdx.x, wv = tid >> 6, lane = tid & 63;
    const int moff = (wv & 1) * 64, noff = (wv >> 1) * 64;
    const int e0 = wv * 1024 + lane * 8, e1 = e0 + 512;
    const short* a0 = Ae + (size_t)(m0 + (e0 >> 5)) * K + (e0 & 31);
    const short* a1 = Ae + (size_t)(m0 + (e1 >> 5)) * K + (e1 & 31);
    const short* b0 = We + (size_t)(n0 + (e0 >> 5)) * K + (e0 & 31);
    const short* b1 = We + (size_t)(n0 + (e1 >> 5)) * K + (e1 & 31);
    short* sa0 = &sA[wv * 1024];  short* sa1 = &sA[wv * 1024 + 512];
    short* sb0 = &sB[wv * 1024];  short* sb1 = &sB[wv * 1024 + 512];

    f32x4 acc[4][4] = {};
    const int lr = lane & 15, lk = (lane >> 4) * 8;

    for (int kk = 0; kk < K; kk += 32){
        gload16(a0 + kk, sa0); gload16(a1 + kk, sa1);
        gload16(b0 + kk, sb0); gload16(b1 + kk, sb1);
        __syncthreads();
        short8 ar[4], br[4];
        #pragma unroll
        for (int i = 0; i < 4; ++i) ar[i] = *(const short8*)&sA[(moff + i*16 + lr) * 32 + lk];
        #pragma unroll
        for (int i = 0; i < 4; ++i) br[i] = *(const short8*)&sB[(noff + i*16 + lr) * 32 + lk];
        #pragma unroll
        for (int ai = 0; ai < 4; ++ai)
            #pragma unroll
            for (int bi = 0; bi < 4; ++bi)
                acc[ai][bi] = __builtin_amdgcn_mfma_f32_16x16x32_bf16(ar[ai], br[bi], acc[ai][bi], 0, 0, 0);
        __syncthreads();
    }

    #pragma unroll
    for (int ai = 0; ai < 4; ++ai){
        #pragma unroll
        for (int bi = 0; bi < 4; ++bi){
            int col = n0 + noff + bi*16 + lr;
            float bv = bias[dir * G3 + col];
            #pragma unroll
            for (int r = 0; r < 4; ++r){
                int row = m0 + moff + ai*16 + ((lane >> 4) << 2) + r;
                out[(size_t)row * G3 + col] = f2b(acc[ai][bi][r] + bv);
            }
        }
    }
}

// ---------------- persistent chunk recurrence ----------------
// grid (32, 2): blockIdx.x = ug*4 + bg  (8 unit-groups x 4 batch-groups), dir = y.
// block 256 (4 waves). Wave wv: units [ug*64+wv*16, +16) x 3 gates, rows [bg*32, +32)
// (2 M-tiles). Whh slice resident in 192 VGPRs. h exchanged via global bf16 hbb
// (double-buffered by step parity) + per-(dir,bg) 8-WG spin barrier.
__global__ __launch_bounds__(256, 1) void rec_kernel(
    const short* __restrict__ gxc,   // [2][SCH*128][1536] bf16 (b_ih folded)
    const short* __restrict__ Whh,   // [2*1536][512] bf16
    const float* __restrict__ bhh,   // [2*1536] fp32
    short* __restrict__ xout,        // [T][B][1024] bf16
    float* __restrict__ hfm,         // [2][128][512] fp32 master (cross-launch)
    short* __restrict__ hbb,         // [2 parity][2 dir][128][512] bf16
    int* __restrict__ bar,           // per (dir,bg): {cnt, gen} stride 32 ints
    int t0f, int t0b_hi, int first)
{
    const int tid = threadIdx.x, wv = tid >> 6, lane = tid & 63;
    const int ug = blockIdx.x >> 2, bg = blockIdx.x & 3, dir = blockIdx.y;
    const int u0 = ug * 64 + wv * 16;    // wave's 16 units
    const int m0 = bg * 32;              // WG's 32 batch rows
    const int lr = lane & 15, lk = (lane >> 4) * 8;
    const int crow = (lane >> 4) * 4;

    // ---- resident weight fragments: 3 gates x 16 k-steps = 192 VGPRs
    const short* Wd = Whh + (size_t)dir * G3 * H_;
    short8 wreg[3][16];
    #pragma unroll
    for (int g = 0; g < 3; ++g)
        #pragma unroll
        for (int kk = 0; kk < 16; ++kk)
            wreg[g][kk] = *(const short8*)&Wd[(size_t)(g*H_ + u0 + lr) * H_ + kk*32 + lk];

    float bh[3];
    #pragma unroll
    for (int g = 0; g < 3; ++g) bh[g] = bhh[dir*G3 + g*H_ + u0 + lr];

    float hreg[2][4];
    #pragma unroll
    for (int mt = 0; mt < 2; ++mt)
        #pragma unroll
        for (int r = 0; r < 4; ++r)
            hreg[mt][r] = first ? 0.f
                : hfm[((size_t)dir*B_ + m0 + mt*16 + crow + r)*H_ + u0 + lr];

    int* cnt = bar + (dir*4 + bg) * 32;
    int* gen = cnt + 16;
    const short* gxd = gxc + (size_t)dir * ((size_t)SCH * B_ * G3);

    for (int sl = 0; sl < SCH; ++sl){
        const int t  = dir ? (t0b_hi - sl) : (t0f + sl);
        const int tl = dir ? (SCH - 1 - sl) : sl;
        const int rp = sl & 1;

        // gate-input loads (independent of h) — issued early
        const short* gb = gxd + ((size_t)(tl * B_) + m0 + crow) * G3 + u0 + lr;
        float gv[3][2][4];
        #pragma unroll
        for (int g = 0; g < 3; ++g)
            #pragma unroll
            for (int mt = 0; mt < 2; ++mt)
                #pragma unroll
                for (int r = 0; r < 4; ++r)
                    gv[g][mt][r] = b2f(gb[(size_t)(mt*16 + r) * G3 + g * H_]);

        // recurrent GEMM: A-frags (h rows) from hbb[rp][dir], B resident
        const short* hread = hbb + ((size_t)(rp*2 + dir) * B_) * H_;
        f32x4 acc[3][2] = {};
        #pragma unroll
        for (int kk = 0; kk < 16; ++kk){
            short8 a0 = *(const short8*)&hread[(size_t)(m0 + lr) * H_ + kk*32 + lk];
            short8 a1 = *(const short8*)&hread[(size_t)(m0 + 16 + lr) * H_ + kk*32 + lk];
            #pragma unroll
            for (int g = 0; g < 3; ++g){
                acc[g][0] = __builtin_amdgcn_mfma_f32_16x16x32_bf16(a0, wreg[g][kk], acc[g][0], 0, 0, 0);
                acc[g][1] = __builtin_amdgcn_mfma_f32_16x16x32_bf16(a1, wreg[g][kk], acc[g][1], 0, 0, 0);
            }
        }

        // gates + h update (lane: unit u0+lr fixed; 2 M-tiles x 4 rows)
        short* hwr = hbb + ((size_t)((rp^1)*2 + dir) * B_) * H_;
        #pragma unroll
        for (int mt = 0; mt < 2; ++mt){
            #pragma unroll
            for (int r = 0; r < 4; ++r){
                float gr = acc[0][mt][r] + bh[0] + gv[0][mt][r];
                float gz = acc[1][mt][r] + bh[1] + gv[1][mt][r];
                float gn = acc[2][mt][r] + bh[2];
                float xn = gv[2][mt][r];
                float rg = 1.f / (1.f + __expf(-gr));
                float zg = 1.f / (1.f + __expf(-gz));
                float e2 = __expf(2.f * (xn + rg * gn));
                float ng = 1.f - 2.f / (e2 + 1.f);            // tanh, inf-safe
                float hn = (1.f - zg) * ng + zg * hreg[mt][r];
                hreg[mt][r] = hn;
                short h16 = f2b(hn);
                const int row = m0 + mt*16 + crow + r;
                hwr[(size_t)row * H_ + u0 + lr] = h16;
                xout[((size_t)t * B_ + row) * 1024 + dir*H_ + u0 + lr] = h16;
            }
        }

        // per-(dir,bg) barrier: this bg's h writes visible to its 8 producer WGs
        __threadfence();
        __syncthreads();
        if (tid == 0){
            int g0 = __hip_atomic_load(gen, __ATOMIC_RELAXED, __HIP_MEMORY_SCOPE_AGENT);
            int a  = __hip_atomic_fetch_add(cnt, 1, __ATOMIC_ACQ_REL, __HIP_MEMORY_SCOPE_AGENT);
            if (a == BGRP - 1){
                __hip_atomic_store(cnt, 0, __ATOMIC_RELAXED, __HIP_MEMORY_SCOPE_AGENT);
                __hip_atomic_store(gen, g0 + 1, __ATOMIC_RELEASE, __HIP_MEMORY_SCOPE_AGENT);
            } else {
                while (__hip_atomic_load(gen, __ATOMIC_ACQUIRE, __HIP_MEMORY_SCOPE_AGENT) == g0)
                    __builtin_amdgcn_s_sleep(1);
            }
        }
        __syncthreads();
    }

    // persist fp32 master across chunk launches
    #pragma unroll
    for (int mt = 0; mt < 2; ++mt)
        #pragma unroll
        for (int r = 0; r < 4; ++r)
            hfm[((size_t)dir*B_ + m0 + mt*16 + crow + r)*H_ + u0 + lr] = hreg[mt][r];
}

// ---------------- final FC + sigmoid ----------------
__global__ void fc_kernel(const short* __restrict__ h, const float* __restrict__ w,
                          const float* __restrict__ b, float* __restrict__ out){
    int wid = threadIdx.x >> 6, lane = threadIdx.x & 63;
    int tb = blockIdx.x * 4 + wid;
    const short* hp = h + (size_t)tb * 1024 + lane * 16;
    float s = 0.f;
    #pragma unroll
    for (int c = 0; c < 2; ++c){
        short8 v = *(const short8*)(hp + c * 8);
        #pragma unroll
        for (int e = 0; e < 8; ++e) s += b2f(v[e]) * w[lane * 16 + c * 8 + e];
    }
    #pragma unroll
    for (int o = 32; o; o >>= 1) s += __shfl_down(s, o);
    if (lane == 0) out[tb] = 1.f / (1.f + __expf(-(s + b[0])));
}

extern "C" void kernel_launch(void* const* d_in, const int* in_sizes, int n_in,
                              void* d_out, int out_size, void* d_ws, size_t ws_size,
                              hipStream_t stream){
    const float* input_seq = (const float*)d_in[0];
    const float* W_ih0 = (const float*)d_in[1];
    const float* W_hh0 = (const float*)d_in[2];
    const float* b_ih0 = (const float*)d_in[3];
    const float* b_hh0 = (const float*)d_in[4];
    const float* W_ih  = (const float*)d_in[5];
    const float* W_hh  = (const float*)d_in[6];
    const float* b_ih  = (const float*)d_in[7];
    const float* b_hh  = (const float*)d_in[8];
    const float* fc_w  = (const float*)d_in[9];
    const float* fc_b  = (const float*)d_in[10];
    (void)in_sizes; (void)n_in; (void)out_size; (void)ws_size;

    char* ws = (char*)d_ws;
    size_t off = 0;
    auto alloc = [&](size_t bytes) -> char* {
        char* p = ws + off; off += (bytes + 255) & ~(size_t)255; return p;
    };
    short* actA = (short*)alloc((size_t)T_*B_*1024 * 2);          // 67.1 MB
    short* actB = (short*)alloc((size_t)T_*B_*1024 * 2);          // 67.1 MB
    short* gxc  = (short*)alloc((size_t)2*SCH*B_*G3 * 2);         // 25.2 MB
    short* wihl = (short*)alloc((size_t)2*G3*1024 * 2);           // 6.3 MB
    short* whhl = (short*)alloc((size_t)2*G3*H_ * 2);             // 3.1 MB
    float* hfm  = (float*)alloc((size_t)2*B_*H_ * 4);             // 0.5 MB
    short* hbb  = (short*)alloc((size_t)2*2*B_*H_ * 2);           // 0.5 MB
    int*   bar  = (int*)alloc(4096);

    hipMemsetAsync(bar, 0, 4096, stream);

    auto cvt = [&](const float* s, short* d, size_t n){
        int blocks = (int)((n/4 + 255) / 256); if (blocks > 4096) blocks = 4096;
        hipLaunchKernelGGL(cvt_f32_to_bf16, dim3(blocks), dim3(256), 0, stream, s, d, (int)n);
    };

    // layer-0 input as [T*B][128] bf16 in actB's head
    cvt(input_seq, actB, (size_t)T_*B_*128);

    for (int l = 0; l < 5; ++l){
        const int K = l ? 1024 : 128;
        cvt(l ? W_ih + (size_t)(l-1)*2*G3*1024 : W_ih0, wihl, (size_t)2*G3*K);
        cvt(l ? W_hh + (size_t)(l-1)*2*G3*H_   : W_hh0, whhl, (size_t)2*G3*H_);
        const short* IN  = (l & 1) ? actA : actB;
        short*       OUT = (l & 1) ? actB : actA;
        const float* bi = l ? b_ih + (size_t)(l-1)*2*G3 : b_ih0;
        const float* bh = l ? b_hh + (size_t)(l-1)*2*G3 : b_hh0;

        hipMemsetAsync(hbb, 0, (size_t)2*2*B_*H_*2, stream);   // h(t=0)=0, both parities

        for (int q = 0; q < NCH; ++q){
            const int t0f    = SCH * q;
            const int t0b_hi = T_ - 1 - SCH * q;
            const int t0b_lo = t0b_hi - SCH + 1;
            hipLaunchKernelGGL(gx_gemm, dim3(SCH*B_/128, G3/128, 2), dim3(256), 0, stream,
                               IN, wihl, bi, gxc, K, t0f, t0b_lo);
            hipLaunchKernelGGL(rec_kernel, dim3(RWG, 2), dim3(256), 0, stream,
                               gxc, whhl, bh, OUT, hfm, hbb, bar, t0f, t0b_hi, q == 0);
        }
    }
    // layer 4 wrote actA
    hipLaunchKernelGGL(fc_kernel, dim3((T_*B_)/4), dim3(256), 0, stream,
                       actA, fc_w, fc_b, (float*)d_out);
}

// Round 6
// 6798.837 us; speedup vs baseline: 10.0798x; 4.0170x over previous
//
#include <hip/hip_runtime.h>
#include <hip/hip_bf16.h>

#define T_ 256
#define B_ 128
#define H_ 512
#define G3 1536
#define SCH 32      // timesteps per chunk
#define NCH 8       // chunks per layer
#define RWG 32      // rec WGs per direction (8 unit-groups x 4 batch-groups)
#define BGRP 8      // WGs per barrier group (same dir, same bg, all ug)

typedef __attribute__((ext_vector_type(8))) short short8;
typedef __attribute__((ext_vector_type(4))) short short4v;
typedef __attribute__((ext_vector_type(4))) float f32x4;

static __device__ __forceinline__ float b2f(short s){
    unsigned u = ((unsigned)(unsigned short)s) << 16;
    return __builtin_bit_cast(float, u);
}
static __device__ __forceinline__ short f2b(float f){
    __hip_bfloat16 h = __float2bfloat16(f);   // RNE
    return __builtin_bit_cast(short, h);
}
static __device__ __forceinline__ void gload16(const void* g, void* l){
    __builtin_amdgcn_global_load_lds(
        (__attribute__((address_space(1))) void*)(void*)g,
        (__attribute__((address_space(3))) void*)l, 16, 0, 0);
}
// coherent (device-scope) 16B load: bypasses stale L1/L2 (sc0 sc1)
static __device__ __forceinline__ short8 gload_sc(const short* p){
    short8 v;
    asm volatile("global_load_dwordx4 %0, %1, off sc0 sc1"
                 : "=v"(v) : "v"(p) : "memory");
    return v;
}
// coherent write-through 2B store
static __device__ __forceinline__ void gstore_sc(short* p, short v){
    asm volatile("global_store_short %0, %1, off sc0 sc1"
                 :: "v"(p), "v"(v) : "memory");
}
static __device__ __forceinline__ void wait_vm0(){
    asm volatile("s_waitcnt vmcnt(0)" ::: "memory");
}

// ---------------- fp32 -> bf16 conversion ----------------
__global__ void cvt_f32_to_bf16(const float* __restrict__ src, short* __restrict__ dst, int n){
    int i = (blockIdx.x * blockDim.x + threadIdx.x) * 4;
    int stride = gridDim.x * blockDim.x * 4;
    for (; i + 3 < n; i += stride){
        float4 v = *(const float4*)(src + i);
        short4v o;
        o[0] = f2b(v.x); o[1] = f2b(v.y); o[2] = f2b(v.z); o[3] = f2b(v.w);
        *(short4v*)(dst + i) = o;
    }
}

// ---------------- gx chunk GEMM (m97-style 128x128 tile, bf16 out) ----------------
__global__ __launch_bounds__(256) void gx_gemm(
    const short* __restrict__ A,     // [T*B][K] bf16
    const short* __restrict__ W,     // [2*1536][K] bf16
    const float* __restrict__ bias,  // [2*1536] fp32
    short* __restrict__ gxc,         // [2][SCH*128][1536] bf16
    int K, int t0f, int t0b_lo)
{
    __shared__ __align__(16) short sA[4096];   // [128][32]
    __shared__ __align__(16) short sB[4096];
    const int dir = blockIdx.z;
    const int t0 = dir ? t0b_lo : t0f;
    const int m0 = blockIdx.x * 128;
    const int n0 = blockIdx.y * 128;
    const short* Ae = A + (size_t)(t0 * B_) * K;
    const short* We = W + (size_t)dir * G3 * K;
    short* out = gxc + (size_t)dir * ((size_t)SCH * B_ * G3);

    const int tid = threadIdx.x, wv = tid >> 6, lane = tid & 63;
    const int moff = (wv & 1) * 64, noff = (wv >> 1) * 64;
    const int e0 = wv * 1024 + lane * 8, e1 = e0 + 512;
    const short* a0 = Ae + (size_t)(m0 + (e0 >> 5)) * K + (e0 & 31);
    const short* a1 = Ae + (size_t)(m0 + (e1 >> 5)) * K + (e1 & 31);
    const short* b0 = We + (size_t)(n0 + (e0 >> 5)) * K + (e0 & 31);
    const short* b1 = We + (size_t)(n0 + (e1 >> 5)) * K + (e1 & 31);
    short* sa0 = &sA[wv * 1024];  short* sa1 = &sA[wv * 1024 + 512];
    short* sb0 = &sB[wv * 1024];  short* sb1 = &sB[wv * 1024 + 512];

    f32x4 acc[4][4] = {};
    const int lr = lane & 15, lk = (lane >> 4) * 8;

    for (int kk = 0; kk < K; kk += 32){
        gload16(a0 + kk, sa0); gload16(a1 + kk, sa1);
        gload16(b0 + kk, sb0); gload16(b1 + kk, sb1);
        __syncthreads();
        short8 ar[4], br[4];
        #pragma unroll
        for (int i = 0; i < 4; ++i) ar[i] = *(const short8*)&sA[(moff + i*16 + lr) * 32 + lk];
        #pragma unroll
        for (int i = 0; i < 4; ++i) br[i] = *(const short8*)&sB[(noff + i*16 + lr) * 32 + lk];
        #pragma unroll
        for (int ai = 0; ai < 4; ++ai)
            #pragma unroll
            for (int bi = 0; bi < 4; ++bi)
                acc[ai][bi] = __builtin_amdgcn_mfma_f32_16x16x32_bf16(ar[ai], br[bi], acc[ai][bi], 0, 0, 0);
        __syncthreads();
    }

    #pragma unroll
    for (int ai = 0; ai < 4; ++ai){
        #pragma unroll
        for (int bi = 0; bi < 4; ++bi){
            int col = n0 + noff + bi*16 + lr;
            float bv = bias[dir * G3 + col];
            #pragma unroll
            for (int r = 0; r < 4; ++r){
                int row = m0 + moff + ai*16 + ((lane >> 4) << 2) + r;
                out[(size_t)row * G3 + col] = f2b(acc[ai][bi][r] + bv);
            }
        }
    }
}

// ---------------- persistent chunk recurrence ----------------
// grid (32, 2): blockIdx.x = ug*4+bg. block 256 (4 waves). Wave wv: units
// [ug*64+wv*16,+16) x 3 gates (Whh slice resident in 192 regs), rows [bg*32,+32).
// h exchange: sc0/sc1 coherent stores+loads through hbb (parity double-buffered),
// monotonic relaxed per-(dir,bg) arrival counter — NO cache-wide fences.
__global__ __launch_bounds__(256, 1) void rec_kernel(
    const short* __restrict__ gxc,   // [2][SCH*128][1536] bf16 (b_ih folded)
    const short* __restrict__ Whh,   // [2*1536][512] bf16
    const float* __restrict__ bhh,   // [2*1536] fp32
    short* __restrict__ xout,        // [T][B][1024] bf16
    float* __restrict__ hfm,         // [2][128][512] fp32 master (cross-launch)
    short* __restrict__ hbb,         // [2 parity][2 dir][128][512] bf16
    int* __restrict__ bar,           // per (dir,bg): monotonic counter, stride 32 ints
    int t0f, int t0b_hi, int first, int base)   // base = q*SCH steps already counted
{
    __shared__ __align__(16) short lds_h[32 * 520];
    const int tid = threadIdx.x, wv = tid >> 6, lane = tid & 63;
    const int ug = blockIdx.x >> 2, bg = blockIdx.x & 3, dir = blockIdx.y;
    const int u0 = ug * 64 + wv * 16;
    const int m0 = bg * 32;
    const int lr = lane & 15, lk = (lane >> 4) * 8;
    const int crow = (lane >> 4) * 4;

    // resident weight fragments: 3 gates x 16 k-steps
    const short* Wd = Whh + (size_t)dir * G3 * H_;
    short8 wreg[3][16];
    #pragma unroll
    for (int g = 0; g < 3; ++g)
        #pragma unroll
        for (int kk = 0; kk < 16; ++kk)
            wreg[g][kk] = *(const short8*)&Wd[(size_t)(g*H_ + u0 + lr) * H_ + kk*32 + lk];

    float bh[3];
    #pragma unroll
    for (int g = 0; g < 3; ++g) bh[g] = bhh[dir*G3 + g*H_ + u0 + lr];

    float hreg[2][4];
    #pragma unroll
    for (int mt = 0; mt < 2; ++mt)
        #pragma unroll
        for (int r = 0; r < 4; ++r)
            hreg[mt][r] = first ? 0.f
                : hfm[((size_t)dir*B_ + m0 + mt*16 + crow + r)*H_ + u0 + lr];

    int* cnt = bar + (dir*4 + bg) * 32;
    const short* gxd = gxc + (size_t)dir * ((size_t)SCH * B_ * G3);

    // staging role: thread stages row srow, 8 chunks of 8 units strided 64
    const int srow = tid >> 3, scol0 = (tid & 7) * 8;

    // prefetch gate inputs for step 0
    float gv[3][2][4];
    {
        const int tl0 = dir ? (SCH - 1) : 0;
        const short* gb = gxd + ((size_t)(tl0 * B_) + m0 + crow) * G3 + u0 + lr;
        #pragma unroll
        for (int g = 0; g < 3; ++g)
            #pragma unroll
            for (int mt = 0; mt < 2; ++mt)
                #pragma unroll
                for (int r = 0; r < 4; ++r)
                    gv[g][mt][r] = b2f(gb[(size_t)(mt*16 + r) * G3 + g * H_]);
    }

    for (int sl = 0; sl < SCH; ++sl){
        const int t  = dir ? (t0b_hi - sl) : (t0f + sl);
        const int rp = sl & 1;

        // ---- stage h[rp] tile (32 rows x 512 units) into LDS via coherent loads
        {
            const short* hsrc = hbb + ((size_t)(rp*2 + dir) * B_ + m0) * H_;
            short8 hv[8];
            #pragma unroll
            for (int c = 0; c < 8; ++c)
                hv[c] = gload_sc(hsrc + (size_t)srow * H_ + scol0 + c*64);
            wait_vm0();
            #pragma unroll
            for (int c = 0; c < 8; ++c)
                *(short8*)&lds_h[srow * 520 + scol0 + c*64] = hv[c];
        }
        __syncthreads();

        // ---- recurrent GEMM from LDS, B resident
        f32x4 acc[3][2] = {};
        #pragma unroll
        for (int kk = 0; kk < 16; ++kk){
            short8 a0 = *(const short8*)&lds_h[(lr)      * 520 + kk*32 + lk];
            short8 a1 = *(const short8*)&lds_h[(16 + lr) * 520 + kk*32 + lk];
            #pragma unroll
            for (int g = 0; g < 3; ++g){
                acc[g][0] = __builtin_amdgcn_mfma_f32_16x16x32_bf16(a0, wreg[g][kk], acc[g][0], 0, 0, 0);
                acc[g][1] = __builtin_amdgcn_mfma_f32_16x16x32_bf16(a1, wreg[g][kk], acc[g][1], 0, 0, 0);
            }
        }

        // ---- gates + h update; coherent h store, plain xout store
        short* hwr = hbb + ((size_t)((rp^1)*2 + dir) * B_) * H_;
        #pragma unroll
        for (int mt = 0; mt < 2; ++mt){
            #pragma unroll
            for (int r = 0; r < 4; ++r){
                float gr = acc[0][mt][r] + bh[0] + gv[0][mt][r];
                float gz = acc[1][mt][r] + bh[1] + gv[1][mt][r];
                float gn = acc[2][mt][r] + bh[2];
                float xn = gv[2][mt][r];
                float rg = 1.f / (1.f + __expf(-gr));
                float zg = 1.f / (1.f + __expf(-gz));
                float e2 = __expf(2.f * (xn + rg * gn));
                float ng = 1.f - 2.f / (e2 + 1.f);            // tanh, inf-safe
                float hn = (1.f - zg) * ng + zg * hreg[mt][r];
                hreg[mt][r] = hn;
                short h16 = f2b(hn);
                const int row = m0 + mt*16 + crow + r;
                gstore_sc(hwr + (size_t)row * H_ + u0 + lr, h16);
                xout[((size_t)t * B_ + row) * 1024 + dir*H_ + u0 + lr] = h16;
            }
        }

        // ---- arrive: h stores acked at coherence point, then count
        wait_vm0();
        __syncthreads();
        if (tid == 0)
            __hip_atomic_fetch_add(cnt, 1, __ATOMIC_RELAXED, __HIP_MEMORY_SCOPE_AGENT);

        // ---- prefetch next step's gate inputs while waiting
        if (sl + 1 < SCH){
            const int tln = dir ? (SCH - 2 - sl) : (sl + 1);
            const short* gb = gxd + ((size_t)(tln * B_) + m0 + crow) * G3 + u0 + lr;
            #pragma unroll
            for (int g = 0; g < 3; ++g)
                #pragma unroll
                for (int mt = 0; mt < 2; ++mt)
                    #pragma unroll
                    for (int r = 0; r < 4; ++r)
                        gv[g][mt][r] = b2f(gb[(size_t)(mt*16 + r) * G3 + g * H_]);
        }

        // ---- wait: all 8 producers of this (dir,bg) group done with step sl
        if (tid == 0){
            const int tgt = (base + sl + 1) * BGRP;
            while (__hip_atomic_load(cnt, __ATOMIC_RELAXED, __HIP_MEMORY_SCOPE_AGENT) < tgt)
                __builtin_amdgcn_s_sleep(1);
        }
        __syncthreads();
    }

    // persist fp32 master across chunk launches
    #pragma unroll
    for (int mt = 0; mt < 2; ++mt)
        #pragma unroll
        for (int r = 0; r < 4; ++r)
            hfm[((size_t)dir*B_ + m0 + mt*16 + crow + r)*H_ + u0 + lr] = hreg[mt][r];
}

// ---------------- final FC + sigmoid ----------------
__global__ void fc_kernel(const short* __restrict__ h, const float* __restrict__ w,
                          const float* __restrict__ b, float* __restrict__ out){
    int wid = threadIdx.x >> 6, lane = threadIdx.x & 63;
    int tb = blockIdx.x * 4 + wid;
    const short* hp = h + (size_t)tb * 1024 + lane * 16;
    float s = 0.f;
    #pragma unroll
    for (int c = 0; c < 2; ++c){
        short8 v = *(const short8*)(hp + c * 8);
        #pragma unroll
        for (int e = 0; e < 8; ++e) s += b2f(v[e]) * w[lane * 16 + c * 8 + e];
    }
    #pragma unroll
    for (int o = 32; o; o >>= 1) s += __shfl_down(s, o);
    if (lane == 0) out[tb] = 1.f / (1.f + __expf(-(s + b[0])));
}

extern "C" void kernel_launch(void* const* d_in, const int* in_sizes, int n_in,
                              void* d_out, int out_size, void* d_ws, size_t ws_size,
                              hipStream_t stream){
    const float* input_seq = (const float*)d_in[0];
    const float* W_ih0 = (const float*)d_in[1];
    const float* W_hh0 = (const float*)d_in[2];
    const float* b_ih0 = (const float*)d_in[3];
    const float* b_hh0 = (const float*)d_in[4];
    const float* W_ih  = (const float*)d_in[5];
    const float* W_hh  = (const float*)d_in[6];
    const float* b_ih  = (const float*)d_in[7];
    const float* b_hh  = (const float*)d_in[8];
    const float* fc_w  = (const float*)d_in[9];
    const float* fc_b  = (const float*)d_in[10];
    (void)in_sizes; (void)n_in; (void)out_size; (void)ws_size;

    char* ws = (char*)d_ws;
    size_t off = 0;
    auto alloc = [&](size_t bytes) -> char* {
        char* p = ws + off; off += (bytes + 255) & ~(size_t)255; return p;
    };
    short* actA = (short*)alloc((size_t)T_*B_*1024 * 2);          // 67.1 MB
    short* actB = (short*)alloc((size_t)T_*B_*1024 * 2);          // 67.1 MB
    short* gxc  = (short*)alloc((size_t)2*SCH*B_*G3 * 2);         // 25.2 MB
    short* wihl = (short*)alloc((size_t)2*G3*1024 * 2);           // 6.3 MB
    short* whhl = (short*)alloc((size_t)2*G3*H_ * 2);             // 3.1 MB
    float* hfm  = (float*)alloc((size_t)2*B_*H_ * 4);             // 0.5 MB
    short* hbb  = (short*)alloc((size_t)2*2*B_*H_ * 2);           // 0.5 MB
    int*   bar  = (int*)alloc(4096);

    auto cvt = [&](const float* s, short* d, size_t n){
        int blocks = (int)((n/4 + 255) / 256); if (blocks > 4096) blocks = 4096;
        hipLaunchKernelGGL(cvt_f32_to_bf16, dim3(blocks), dim3(256), 0, stream, s, d, (int)n);
    };

    // layer-0 input as [T*B][128] bf16 in actB's head
    cvt(input_seq, actB, (size_t)T_*B_*128);

    for (int l = 0; l < 5; ++l){
        const int K = l ? 1024 : 128;
        cvt(l ? W_ih + (size_t)(l-1)*2*G3*1024 : W_ih0, wihl, (size_t)2*G3*K);
        cvt(l ? W_hh + (size_t)(l-1)*2*G3*H_   : W_hh0, whhl, (size_t)2*G3*H_);
        const short* IN  = (l & 1) ? actA : actB;
        short*       OUT = (l & 1) ? actB : actA;
        const float* bi = l ? b_ih + (size_t)(l-1)*2*G3 : b_ih0;
        const float* bh = l ? b_hh + (size_t)(l-1)*2*G3 : b_hh0;

        hipMemsetAsync(hbb, 0, (size_t)2*2*B_*H_*2, stream);   // h(t=0)=0, both parities
        hipMemsetAsync(bar, 0, 4096, stream);                  // arrival counters

        for (int q = 0; q < NCH; ++q){
            const int t0f    = SCH * q;
            const int t0b_hi = T_ - 1 - SCH * q;
            const int t0b_lo = t0b_hi - SCH + 1;
            hipLaunchKernelGGL(gx_gemm, dim3(SCH*B_/128, G3/128, 2), dim3(256), 0, stream,
                               IN, wihl, bi, gxc, K, t0f, t0b_lo);
            hipLaunchKernelGGL(rec_kernel, dim3(RWG, 2), dim3(256), 0, stream,
                               gxc, whhl, bh, OUT, hfm, hbb, bar, t0f, t0b_hi, q == 0, q*SCH);
        }
    }
    // layer 4 wrote actA
    hipLaunchKernelGGL(fc_kernel, dim3((T_*B_)/4), dim3(256), 0, stream,
                       actA, fc_w, fc_b, (float*)d_out);
}